// Round 9
// baseline (379.205 us; speedup 1.0000x reference)
//
#include <hip/hip_runtime.h>

#define SEQ 2048
#define BB 4
#define DM 1024
#define NH 16
#define DH 64
#define ROWS (BB*SEQ)

#define BM 128
#define BN 128
#define BK 32
#define KSTEPS (DM / BK)

#define KVBLK 64
#define NT (SEQ / KVBLK)
#define NBUF 3

typedef _Float16 f16;
typedef _Float16 f16x8 __attribute__((ext_vector_type(8)));
typedef _Float16 f16x4 __attribute__((ext_vector_type(4)));
typedef float f32x4 __attribute__((ext_vector_type(4)));
typedef float f32x16 __attribute__((ext_vector_type(16)));
typedef unsigned u32x4 __attribute__((ext_vector_type(4)));

__device__ __forceinline__ f32x4 mfma16(f16x8 a, f16x8 b, f32x4 c) {
    return __builtin_amdgcn_mfma_f32_16x16x32_f16(a, b, c, 0, 0, 0);
}
__device__ __forceinline__ f32x16 mfma32(f16x8 a, f16x8 b, f32x16 c) {
    return __builtin_amdgcn_mfma_f32_32x32x16_f16(a, b, c, 0, 0, 0);
}
__device__ __forceinline__ unsigned pkh(float a, float b) {
    auto h = __builtin_amdgcn_cvt_pkrtz(a, b);   // __fp16 ext_vector(2)
    return __builtin_bit_cast(unsigned, h);
}
// v_permlane32_swap_b32 (vdst=a, vsrc=b):
//   new_a = {lo: a.lo, hi: b.lo};  new_b = {lo: a.hi, hi: b.hi}
__device__ __forceinline__ void plswap(unsigned& a, unsigned& b) {
    auto r = __builtin_amdgcn_permlane32_swap((int)a, (int)b, false, false);
    a = (unsigned)r[0];
    b = (unsigned)r[1];
}
__device__ __forceinline__ float2 plswapf(float x) {
    int xi = __builtin_bit_cast(int, x);
    auto r = __builtin_amdgcn_permlane32_swap(xi, xi, false, false);
    return float2{ __builtin_bit_cast(float, (int)r[0]), __builtin_bit_cast(float, (int)r[1]) };
}
// async global->LDS, 16B per lane; LDS dest = wave-uniform base + lane*16
typedef const __attribute__((address_space(1))) void gvoid;
typedef __attribute__((address_space(3))) void lvoid;
__device__ __forceinline__ void gload16(const f16* g, f16* l) {
    __builtin_amdgcn_global_load_lds((gvoid*)g, (lvoid*)l, 16, 0, 0);
}

// ---------------- weight conversion fp32 -> f16 ----------------
__global__ __launch_bounds__(256) void cvt_weights(
    const float* __restrict__ wq, const float* __restrict__ wk,
    const float* __restrict__ wv, const float* __restrict__ wo,
    f16* __restrict__ oq, f16* __restrict__ ok,
    f16* __restrict__ ov, f16* __restrict__ oo) {
    int i = (blockIdx.x * 256 + threadIdx.x) * 4;
    float4 a = *(const float4*)(wq + i);
    float4 b = *(const float4*)(wk + i);
    float4 c = *(const float4*)(wv + i);
    float4 d = *(const float4*)(wo + i);
    f16x4 va = { (f16)a.x, (f16)a.y, (f16)a.z, (f16)a.w };
    f16x4 vb = { (f16)b.x, (f16)b.y, (f16)b.z, (f16)b.w };
    f16x4 vc = { (f16)c.x, (f16)c.y, (f16)c.z, (f16)c.w };
    f16x4 vd = { (f16)d.x, (f16)d.y, (f16)d.z, (f16)d.w };
    *(f16x4*)(oq + i) = va;
    *(f16x4*)(ok + i) = vb;
    *(f16x4*)(ov + i) = vc;
    *(f16x4*)(oo + i) = vd;
}

// ---------------- mask -> packed bitmask (256 u32 words) ----------------
__global__ __launch_bounds__(64) void pack_mask(
    const int* __restrict__ mask, unsigned* __restrict__ pm) {
    int tid = blockIdx.x * 64 + threadIdx.x;   // 0..255
    const int* mp = mask + (size_t)tid * 32;
    unsigned bits = 0;
#pragma unroll
    for (int j = 0; j < 32; ++j) bits |= (mp[j] != 0 ? 1u : 0u) << j;
    pm[tid] = bits;
}

// ---------------- 128x128 GEMM, QKV projection (A fp32, converted in-kernel) ----
// A [M][K] fp32, W [N][K] f16. out = (A.W^T + bias)*scale
// mode 0: write [b][h][s][dh]   (q, k);  mode 2: write [b][h][dh][s]  (v^T)
__global__ __launch_bounds__(256) void gemm_proj(
    const float* __restrict__ A, const f16* __restrict__ W,
    const float* __restrict__ bias, f16* __restrict__ out,
    float scale, int mode) {
    __shared__ f16 lds_a[2][BM][BK + 8];   // padded: 2-way-max read conflicts
    __shared__ f16 lds_b[2][BN][BK];
    const int tid = threadIdx.x;
    const int lane = tid & 63;
    const int wv = tid >> 6;
    const int wr = wv >> 1, wc = wv & 1;
    const int lo = lane & 15, hi = lane >> 4;
    const int rowbase = blockIdx.x * BM;
    const int colbase = blockIdx.y * BN;
    const int ar = tid >> 1;            // A row 0..127
    const int ac = (tid & 1) * 16;      // A col half

    f32x4 acc[4][4];
#pragma unroll
    for (int m = 0; m < 4; ++m)
#pragma unroll
        for (int n = 0; n < 4; ++n) acc[m][n] = (f32x4){0.f, 0.f, 0.f, 0.f};

    float4 av0, av1, av2, av3;
#define LOAD_A(k0)                                                                  \
    {                                                                               \
        const float* ap_ = A + (size_t)(rowbase + ar) * DM + (k0) + ac;             \
        av0 = *(const float4*)(ap_);                                                \
        av1 = *(const float4*)(ap_ + 4);                                            \
        av2 = *(const float4*)(ap_ + 8);                                            \
        av3 = *(const float4*)(ap_ + 12);                                           \
    }
#define WRITE_A(buf)                                                                \
    {                                                                               \
        f16* dp_ = &lds_a[buf][ar][ac];                                             \
        u32x4 t0_ = { pkh(av0.x, av0.y), pkh(av0.z, av0.w),                         \
                      pkh(av1.x, av1.y), pkh(av1.z, av1.w) };                       \
        u32x4 t1_ = { pkh(av2.x, av2.y), pkh(av2.z, av2.w),                         \
                      pkh(av3.x, av3.y), pkh(av3.z, av3.w) };                       \
        *(u32x4*)(dp_) = t0_;                                                       \
        *(u32x4*)(dp_ + 8) = t1_;                                                   \
    }
#define STAGE_W(buf, k0)                                                            \
    {                                                                               \
        int r_ = lane >> 2, kc_ = (lane & 3) * 8;                                   \
        gload16(W + (size_t)(colbase + wv * 16 + r_) * DM + (k0) + kc_,             \
                &lds_b[buf][wv * 16][0]);                                           \
        gload16(W + (size_t)(colbase + (wv + 4) * 16 + r_) * DM + (k0) + kc_,       \
                &lds_b[buf][(wv + 4) * 16][0]);                                     \
    }

    LOAD_A(0)
    STAGE_W(0, 0)
    WRITE_A(0)
    __syncthreads();
    int buf = 0;
    for (int ks = 0; ks < KSTEPS; ++ks) {
        if (ks + 1 < KSTEPS) {
            LOAD_A((ks + 1) * BK)
            STAGE_W(buf ^ 1, (ks + 1) * BK)
        }
        f16x8 af[4], bf[4];
#pragma unroll
        for (int m = 0; m < 4; ++m)
            af[m] = *(const f16x8*)&lds_a[buf][wr * 64 + m * 16 + lo][hi * 8];
#pragma unroll
        for (int n = 0; n < 4; ++n)
            bf[n] = *(const f16x8*)&lds_b[buf][wc * 64 + n * 16 + lo][hi * 8];
#pragma unroll
        for (int m = 0; m < 4; ++m)
#pragma unroll
            for (int n = 0; n < 4; ++n)
                acc[m][n] = mfma16(af[m], bf[n], acc[m][n]);
        if (ks + 1 < KSTEPS) WRITE_A(buf ^ 1)     // vm-wait lands after MFMAs
        __syncthreads();
        buf ^= 1;
    }
#undef LOAD_A
#undef WRITE_A
#undef STAGE_W

#pragma unroll
    for (int n = 0; n < 4; ++n) {
        int col = colbase + wc * 64 + n * 16 + lo;
        float bv = bias[col];
        int hh = col >> 6, dh = col & 63;
#pragma unroll
        for (int m = 0; m < 4; ++m)
#pragma unroll
            for (int r = 0; r < 4; ++r) {
                int row = rowbase + wr * 64 + m * 16 + hi * 4 + r;
                int bi = row >> 11;
                int ss = row & (SEQ - 1);
                float v = (acc[m][n][r] + bv) * scale;
                size_t dst;
                if (mode == 2)
                    dst = (((size_t)(bi * NH + hh) * DH + dh) * SEQ + ss);
                else
                    dst = (((size_t)(bi * NH + hh) * SEQ + ss) * DH + dh);
                out[dst] = (f16)v;
            }
    }
}

// ---------------- m97-style GEMM, output projection + bias + residual ----------
__global__ __launch_bounds__(256) void gemm_oproj(
    const f16* __restrict__ A, const f16* __restrict__ W,
    const float* __restrict__ bo, const float* __restrict__ Qin,
    float* __restrict__ out) {
    __shared__ f16 lds_a[2][BM][BK];
    __shared__ f16 lds_b[2][BN][BK];
    const int lane = threadIdx.x & 63;
    const int wv = threadIdx.x >> 6;
    const int wr = wv >> 1, wc = wv & 1;
    const int lo = lane & 15, hi = lane >> 4;
    const int rowbase = blockIdx.x * BM;
    const int colbase = blockIdx.y * BN;

    f32x4 acc[4][4];
#pragma unroll
    for (int m = 0; m < 4; ++m)
#pragma unroll
        for (int n = 0; n < 4; ++n) acc[m][n] = (f32x4){0.f, 0.f, 0.f, 0.f};

#define STAGE_TILES(buf, k0)                                                        \
    {                                                                               \
        int r_ = lane >> 2, kc_ = (lane & 3) * 8;                                   \
        gload16(A + (size_t)(rowbase + wv * 16 + r_) * DM + (k0) + kc_,             \
                &lds_a[buf][wv * 16][0]);                                           \
        gload16(A + (size_t)(rowbase + (wv + 4) * 16 + r_) * DM + (k0) + kc_,       \
                &lds_a[buf][(wv + 4) * 16][0]);                                     \
        gload16(W + (size_t)(colbase + wv * 16 + r_) * DM + (k0) + kc_,             \
                &lds_b[buf][wv * 16][0]);                                           \
        gload16(W + (size_t)(colbase + (wv + 4) * 16 + r_) * DM + (k0) + kc_,       \
                &lds_b[buf][(wv + 4) * 16][0]);                                     \
    }

    STAGE_TILES(0, 0)
    __syncthreads();
    int buf = 0;
    for (int ks = 0; ks < KSTEPS; ++ks) {
        if (ks + 1 < KSTEPS) STAGE_TILES(buf ^ 1, (ks + 1) * BK)
        f16x8 af[4], bf[4];
#pragma unroll
        for (int m = 0; m < 4; ++m)
            af[m] = *(const f16x8*)&lds_a[buf][wr * 64 + m * 16 + lo][hi * 8];
#pragma unroll
        for (int n = 0; n < 4; ++n)
            bf[n] = *(const f16x8*)&lds_b[buf][wc * 64 + n * 16 + lo][hi * 8];
#pragma unroll
        for (int m = 0; m < 4; ++m)
#pragma unroll
            for (int n = 0; n < 4; ++n)
                acc[m][n] = mfma16(af[m], bf[n], acc[m][n]);
        __syncthreads();
        buf ^= 1;
    }
#undef STAGE_TILES

#pragma unroll
    for (int n = 0; n < 4; ++n) {
        int col = colbase + wc * 64 + n * 16 + lo;
        float bv = bo[col];
#pragma unroll
        for (int m = 0; m < 4; ++m)
#pragma unroll
            for (int r = 0; r < 4; ++r) {
                int row = rowbase + wr * 64 + m * 16 + hi * 4 + r;
                size_t idx = (size_t)row * DM + col;
                out[idx] = acc[m][n][r] + bv + Qin[idx];
            }
    }
}

// ---------------- fused flash attention: 8 waves, 3-buffer counted-vmcnt --------
// grid: (BB*NH, SEQ/256), block 512. Wave wv owns q-rows [q0, q0+32).
// LDS layout per tile: row r of K (or dh-row of V^T) at [r*64], col-block slot s
// holds global cols (s ^ (r&7))*8 .. +8  (XOR swizzle, both sides).
__global__ __launch_bounds__(512, 4) void attn_kernel(
    const f16* __restrict__ q16, const f16* __restrict__ k16,
    const f16* __restrict__ v16t, const unsigned* __restrict__ pm,
    f16* __restrict__ out16) {
    __shared__ f16 smem[NBUF][2][KVBLK * 64];    // 48 KB
    const int tid = threadIdx.x;
    const int lane = tid & 63;
    const int wv = tid >> 6;                     // 0..7
    const int lo = lane & 31, hw = lane >> 5;
    const int bh = blockIdx.x;
    const int b = bh >> 4, hd = bh & 15;
    const int q0 = blockIdx.y * 256 + wv * 32;

    const f16* qp = q16 + ((size_t)bh * SEQ + q0 + lo) * DH + hw * 8;
    const f16* kp = k16 + (size_t)bh * SEQ * DH;
    const f16* vp = v16t + (size_t)bh * DH * SEQ;
    const unsigned* pmb = pm + b * 64;

    const int sr = lane >> 3;        // staging row-in-group 0..7
    const int scb = lane & 7;        // staging slot
    const int cb = scb ^ sr;         // global col-block loaded into slot scb

    f16x8 qb[4];
#pragma unroll
    for (int c = 0; c < 4; ++c) qb[c] = *(const f16x8*)(qp + c * 16);

    f32x16 fz;
#pragma unroll
    for (int i = 0; i < 16; ++i) fz[i] = 0.f;
    f32x16 ctx0 = fz, ctx1 = fz, lacc = fz;
    float m = -3e38f;
    f16x8 ones8;
#pragma unroll
    for (int i = 0; i < 8; ++i) ones8[i] = (f16)1.0f;

    // wave wv stages rows [wv*8, wv*8+8) of K and of V^T: 2 gload16 per tile
#define STAGE(buf, KB)                                                              \
    {                                                                               \
        gload16(kp + (size_t)((KB) + wv * 8 + sr) * DH + cb * 8,                    \
                &smem[buf][0][wv * 512]);                                           \
        gload16(vp + (size_t)(wv * 8 + sr) * SEQ + (KB) + cb * 8,                   \
                &smem[buf][1][wv * 512]);                                           \
    }

    STAGE(0, 0)
    STAGE(1, KVBLK)

    int bc = 0;                       // t % NBUF
    for (int t = 0; t < NT; ++t) {
        // counted wait: own STAGE(t) (2 loads) landed; STAGE(t+1) may stay in flight
        if (t < NT - 1) asm volatile("s_waitcnt vmcnt(2)" ::: "memory");
        else            asm volatile("s_waitcnt vmcnt(0)" ::: "memory");
        __builtin_amdgcn_s_barrier();
        asm volatile("" ::: "memory");

        // ---- K fragments from LDS (swizzled read) ----
        f16x8 kf[2][4];
#pragma unroll
        for (int kt = 0; kt < 2; ++kt)
#pragma unroll
            for (int c = 0; c < 4; ++c) {
                int idx = (kt * 32 + lo) * 64 + ((((2 * c + hw)) ^ (lo & 7)) << 3);
                kf[kt][c] = *(const f16x8*)&smem[bc][0][idx];
            }

        // ---- prefetch 2 tiles ahead ----
        if (t + 2 < NT) {
            int bs = bc + 2; if (bs >= NBUF) bs -= NBUF;
            STAGE(bs, (t + 2) * KVBLK)
        }

        // ---- QK^T (zero-register C) ----
        f32x16 st0, st1;
        __builtin_amdgcn_s_setprio(1);
        st0 = mfma32(kf[0][0], qb[0], fz);
        st0 = mfma32(kf[0][1], qb[1], st0);
        st0 = mfma32(kf[0][2], qb[2], st0);
        st0 = mfma32(kf[0][3], qb[3], st0);
        st1 = mfma32(kf[1][0], qb[0], fz);
        st1 = mfma32(kf[1][1], qb[1], st1);
        st1 = mfma32(kf[1][2], qb[2], st1);
        st1 = mfma32(kf[1][3], qb[3], st1);
        __builtin_amdgcn_s_setprio(0);

        // ---- V fragments (latency hides under softmax) ----
        f16x8 vf[2][4];
#pragma unroll
        for (int kt = 0; kt < 2; ++kt)
#pragma unroll
            for (int c = 0; c < 4; ++c) {
                int idx = (kt * 32 + lo) * 64 + ((((2 * c + hw)) ^ (lo & 7)) << 3);
                vf[kt][c] = *(const f16x8*)&smem[bc][1][idx];
            }

        // ---- mask (packed bits, scalar loads) ----
        unsigned bm0 = pmb[2 * t];
        unsigned bm1 = pmb[2 * t + 1];
        if (bm0 != 0xffffffffu) {
            unsigned bs_ = bm0 >> (hw * 4);
#pragma unroll
            for (int r = 0; r < 16; ++r)
                if (!((bs_ >> ((r & 3) + 8 * (r >> 2))) & 1)) st0[r] = -1e9f;
        }
        if (bm1 != 0xffffffffu) {
            unsigned bs_ = bm1 >> (hw * 4);
#pragma unroll
            for (int r = 0; r < 16; ++r)
                if (!((bs_ >> ((r & 3) + 8 * (r >> 2))) & 1)) st1[r] = -1e9f;
        }

        // ---- online softmax max ----
        float tma = fmaxf(st0[0], st0[1]);
#pragma unroll
        for (int i = 2; i < 16; i += 2) tma = fmaxf(fmaxf(tma, st0[i]), st0[i + 1]);
        float tmb = fmaxf(st1[0], st1[1]);
#pragma unroll
        for (int i = 2; i < 16; i += 2) tmb = fmaxf(fmaxf(tmb, st1[i]), st1[i + 1]);
        float tm = fmaxf(tma, tmb);
        {
            float2 pp = plswapf(tm);
            tm = fmaxf(pp.x, pp.y);
        }

        if (!__all(tm <= m)) {          // defer-max: rescale only on new max
            float mn = fmaxf(m, tm);
            float sc = exp2f(m - mn);
#pragma unroll
            for (int i = 0; i < 16; ++i) { ctx0[i] *= sc; ctx1[i] *= sc; }
            lacc[0] *= sc;
            m = mn;
        }
#pragma unroll
        for (int i = 0; i < 16; ++i) st0[i] = exp2f(st0[i] - m);
#pragma unroll
        for (int i = 0; i < 16; ++i) st1[i] = exp2f(st1[i] - m);

        // ---- P -> B-fragment, PV MFMAs, l via ones-MFMA ----
        __builtin_amdgcn_s_setprio(1);
#define PV_TILE(ST, V0C0, V0C1, V1C0, V1C1)                                        \
        {                                                                          \
            unsigned w0 = pkh(ST[0], ST[1]),   w1 = pkh(ST[2], ST[3]);             \
            unsigned w2 = pkh(ST[4], ST[5]),   w3 = pkh(ST[6], ST[7]);             \
            unsigned w4 = pkh(ST[8], ST[9]),   w5 = pkh(ST[10], ST[11]);           \
            unsigned w6 = pkh(ST[12], ST[13]), w7 = pkh(ST[14], ST[15]);           \
            {                                                                      \
                unsigned a0 = w0, b0 = w2; plswap(a0, b0);                         \
                unsigned a1 = w1, b1 = w3; plswap(a1, b1);                         \
                u32x4 t_ = { a0, a1, b0, b1 };                                     \
                f16x8 pb = __builtin_bit_cast(f16x8, t_);                          \
                ctx0 = mfma32(V0C0, pb, ctx0);                                     \
                ctx1 = mfma32(V1C0, pb, ctx1);                                     \
                lacc = mfma32(ones8, pb, lacc);                                    \
            }                                                                      \
            {                                                                      \
                unsigned a0 = w4, b0 = w6; plswap(a0, b0);                         \
                unsigned a1 = w5, b1 = w7; plswap(a1, b1);                         \
                u32x4 t_ = { a0, a1, b0, b1 };                                     \
                f16x8 pb = __builtin_bit_cast(f16x8, t_);                          \
                ctx0 = mfma32(V0C1, pb, ctx0);                                     \
                ctx1 = mfma32(V1C1, pb, ctx1);                                     \
                lacc = mfma32(ones8, pb, lacc);                                    \
            }                                                                      \
        }
        PV_TILE(st0, vf[0][0], vf[0][1], vf[1][0], vf[1][1])
        PV_TILE(st1, vf[0][2], vf[0][3], vf[1][2], vf[1][3])
#undef PV_TILE
        __builtin_amdgcn_s_setprio(0);

        bc = (bc + 1 == NBUF) ? 0 : bc + 1;
    }
#undef STAGE

    __syncthreads();   // all waves done with smem tiles before transpose reuse

    // ---- epilogue: divide by l, transpose via LDS (reuse smem), f16 stores ----
    float rl = 1.0f / lacc[0];
    f16* tbp = &smem[0][0][0] + wv * (32 * 66);
#pragma unroll
    for (int u = 0; u < 8; ++u) {
        int d0 = 2 * (u & 1) + 8 * (u >> 1) + 4 * hw;
        unsigned pw0 = pkh(ctx0[2 * u] * rl, ctx0[2 * u + 1] * rl);
        unsigned pw1 = pkh(ctx1[2 * u] * rl, ctx1[2 * u + 1] * rl);
        *(unsigned*)&tbp[lo * 66 + d0] = pw0;
        *(unsigned*)&tbp[lo * 66 + 32 + d0] = pw1;
    }
    __syncthreads();
#pragma unroll
    for (int it = 0; it < 4; ++it) {
        int r = it * 8 + (lane >> 3);
        const unsigned* src = (const unsigned*)(tbp + r * 66);
        int cc = (lane & 7) * 4;
        u32x4 t = { src[cc], src[cc + 1], src[cc + 2], src[cc + 3] };
        f16x8 vvv = __builtin_bit_cast(f16x8, t);
        *(f16x8*)(out16 + ((size_t)(b * SEQ) + q0 + r) * DM + hd * 64 + (lane & 7) * 8) = vvv;
    }
}

// ---------------- in-place LayerNorm ----------------
__global__ __launch_bounds__(256) void ln_kernel(
    float* __restrict__ x, const float* __restrict__ gamma,
    const float* __restrict__ beta) {
    const int lane = threadIdx.x & 63;
    const int wave = threadIdx.x >> 6;
    const int row = blockIdx.x * 4 + wave;
    float* rp = x + (size_t)row * DM;

    float4 v[4];
#pragma unroll
    for (int j = 0; j < 4; ++j) v[j] = ((const float4*)rp)[lane + 64 * j];

    float sum = 0.f;
#pragma unroll
    for (int j = 0; j < 4; ++j) sum += v[j].x + v[j].y + v[j].z + v[j].w;
#pragma unroll
    for (int off = 1; off < 64; off <<= 1) sum += __shfl_xor(sum, off);
    float mean = sum * (1.f / DM);

    float vs = 0.f;
#pragma unroll
    for (int j = 0; j < 4; ++j) {
        float dx = v[j].x - mean, dy = v[j].y - mean, dz = v[j].z - mean, dw = v[j].w - mean;
        vs += dx * dx + dy * dy + dz * dz + dw * dw;
    }
#pragma unroll
    for (int off = 1; off < 64; off <<= 1) vs += __shfl_xor(vs, off);
    float rstd = rsqrtf(vs * (1.f / DM) + 1e-5f);

#pragma unroll
    for (int j = 0; j < 4; ++j) {
        int idx = lane + 64 * j;
        float4 g = ((const float4*)gamma)[idx];
        float4 bt = ((const float4*)beta)[idx];
        float4 o;
        o.x = (v[j].x - mean) * rstd * g.x + bt.x;
        o.y = (v[j].y - mean) * rstd * g.y + bt.y;
        o.z = (v[j].z - mean) * rstd * g.z + bt.z;
        o.w = (v[j].w - mean) * rstd * g.w + bt.w;
        ((float4*)rp)[idx] = o;
    }
}

extern "C" void kernel_launch(void* const* d_in, const int* in_sizes, int n_in,
                              void* d_out, int out_size, void* d_ws, size_t ws_size,
                              hipStream_t stream) {
    const float* Q    = (const float*)d_in[0];
    const float* K    = (const float*)d_in[1];
    const float* V    = (const float*)d_in[2];
    const int*   mask = (const int*)d_in[3];
    const float* Wq   = (const float*)d_in[4];
    const float* bq   = (const float*)d_in[5];
    const float* Wk   = (const float*)d_in[6];
    const float* bk   = (const float*)d_in[7];
    const float* Wv   = (const float*)d_in[8];
    const float* bv   = (const float*)d_in[9];
    const float* Wo   = (const float*)d_in[10];
    const float* bo   = (const float*)d_in[11];
    const float* gamma = (const float*)d_in[12];
    const float* beta  = (const float*)d_in[13];
    float* out = (float*)d_out;

    char* ws = (char*)d_ws;
    const size_t MB = 1024 * 1024;
    f16* wq16 = (f16*)(ws + 0 * MB);
    f16* wk16 = (f16*)(ws + 2 * MB);
    f16* wv16 = (f16*)(ws + 4 * MB);
    f16* wo16 = (f16*)(ws + 6 * MB);
    f16* c16  = (f16*)(ws + 8 * MB);
    f16* q16  = (f16*)(ws + 24 * MB);
    f16* k16  = (f16*)(ws + 40 * MB);
    f16* v16t = (f16*)(ws + 56 * MB);  // total 72 MB

    // packed mask lives in the tail of d_out; oproj overwrites all of out later
    unsigned* pm = (unsigned*)((char*)d_out + (size_t)out_size * 4 - 4096);

    cvt_weights<<<dim3(DM * DM / (256 * 4)), dim3(256), 0, stream>>>(
        Wq, Wk, Wv, Wo, wq16, wk16, wv16, wo16);
    pack_mask<<<dim3(4), dim3(64), 0, stream>>>(mask, pm);

    const dim3 ggrid(ROWS / BM, DM / BN);
    const float qscale = 0.125f * 1.44269504f;   // 1/sqrt(DH) * log2(e)

    gemm_proj<<<ggrid, dim3(256), 0, stream>>>(Q, wq16, bq, q16, qscale, 0);
    gemm_proj<<<ggrid, dim3(256), 0, stream>>>(K, wk16, bk, k16, 1.0f, 0);
    gemm_proj<<<ggrid, dim3(256), 0, stream>>>(V, wv16, bv, v16t, 1.0f, 2);

    attn_kernel<<<dim3(BB * NH, SEQ / 256), dim3(512), 0, stream>>>(
        q16, k16, v16t, pm, c16);

    gemm_oproj<<<ggrid, dim3(256), 0, stream>>>(c16, wo16, bo, Q, out);

    ln_kernel<<<dim3(ROWS / 4), dim3(256), 0, stream>>>(out, gamma, beta);
}

// Round 10
// 316.217 us; speedup vs baseline: 1.1992x; 1.1992x over previous
//
#include <hip/hip_runtime.h>

#define SEQ 2048
#define BB 4
#define DM 1024
#define NH 16
#define DH 64
#define ROWS (BB*SEQ)

#define BM 128
#define BN 128
#define BK 32
#define KSTEPS (DM / BK)

#define KVBLK 32
#define NT (SEQ / KVBLK)
#define NBUF 3

typedef _Float16 f16;
typedef _Float16 f16x8 __attribute__((ext_vector_type(8)));
typedef _Float16 f16x4 __attribute__((ext_vector_type(4)));
typedef float f32x4 __attribute__((ext_vector_type(4)));
typedef float f32x16 __attribute__((ext_vector_type(16)));
typedef unsigned u32x4 __attribute__((ext_vector_type(4)));

__device__ __forceinline__ f32x4 mfma16(f16x8 a, f16x8 b, f32x4 c) {
    return __builtin_amdgcn_mfma_f32_16x16x32_f16(a, b, c, 0, 0, 0);
}
__device__ __forceinline__ f32x16 mfma32(f16x8 a, f16x8 b, f32x16 c) {
    return __builtin_amdgcn_mfma_f32_32x32x16_f16(a, b, c, 0, 0, 0);
}
__device__ __forceinline__ unsigned pkh(float a, float b) {
    auto h = __builtin_amdgcn_cvt_pkrtz(a, b);   // __fp16 ext_vector(2)
    return __builtin_bit_cast(unsigned, h);
}
// v_permlane32_swap_b32 (vdst=a, vsrc=b):
//   new_a = {lo: a.lo, hi: b.lo};  new_b = {lo: a.hi, hi: b.hi}
__device__ __forceinline__ void plswap(unsigned& a, unsigned& b) {
    auto r = __builtin_amdgcn_permlane32_swap((int)a, (int)b, false, false);
    a = (unsigned)r[0];
    b = (unsigned)r[1];
}
__device__ __forceinline__ float2 plswapf(float x) {
    int xi = __builtin_bit_cast(int, x);
    auto r = __builtin_amdgcn_permlane32_swap(xi, xi, false, false);
    return float2{ __builtin_bit_cast(float, (int)r[0]), __builtin_bit_cast(float, (int)r[1]) };
}
// async global->LDS, 16B per lane; LDS dest = wave-uniform base + lane*16
typedef const __attribute__((address_space(1))) void gvoid;
typedef __attribute__((address_space(3))) void lvoid;
__device__ __forceinline__ void gload16(const f16* g, f16* l) {
    __builtin_amdgcn_global_load_lds((gvoid*)g, (lvoid*)l, 16, 0, 0);
}

// ---------------- weight conversion fp32 -> f16 ----------------
__global__ __launch_bounds__(256) void cvt_weights(
    const float* __restrict__ wq, const float* __restrict__ wk,
    const float* __restrict__ wv, const float* __restrict__ wo,
    f16* __restrict__ oq, f16* __restrict__ ok,
    f16* __restrict__ ov, f16* __restrict__ oo) {
    int i = (blockIdx.x * 256 + threadIdx.x) * 4;
    float4 a = *(const float4*)(wq + i);
    float4 b = *(const float4*)(wk + i);
    float4 c = *(const float4*)(wv + i);
    float4 d = *(const float4*)(wo + i);
    f16x4 va = { (f16)a.x, (f16)a.y, (f16)a.z, (f16)a.w };
    f16x4 vb = { (f16)b.x, (f16)b.y, (f16)b.z, (f16)b.w };
    f16x4 vc = { (f16)c.x, (f16)c.y, (f16)c.z, (f16)c.w };
    f16x4 vd = { (f16)d.x, (f16)d.y, (f16)d.z, (f16)d.w };
    *(f16x4*)(oq + i) = va;
    *(f16x4*)(ok + i) = vb;
    *(f16x4*)(ov + i) = vc;
    *(f16x4*)(oo + i) = vd;
}

// ---------------- mask -> packed bitmask (256 u32 words) ----------------
__global__ __launch_bounds__(64) void pack_mask(
    const int* __restrict__ mask, unsigned* __restrict__ pm) {
    int tid = blockIdx.x * 64 + threadIdx.x;   // 0..255
    const int* mp = mask + (size_t)tid * 32;
    unsigned bits = 0;
#pragma unroll
    for (int j = 0; j < 32; ++j) bits |= (mp[j] != 0 ? 1u : 0u) << j;
    pm[tid] = bits;
}

// ---------------- 128x128 GEMM, QKV projection (A fp32, converted in-kernel) ----
__global__ __launch_bounds__(256) void gemm_proj(
    const float* __restrict__ A, const f16* __restrict__ W,
    const float* __restrict__ bias, f16* __restrict__ out,
    float scale, int mode) {
    __shared__ f16 lds_a[2][BM][BK + 8];   // padded: 2-way-max read conflicts
    __shared__ f16 lds_b[2][BN][BK];
    const int tid = threadIdx.x;
    const int lane = tid & 63;
    const int wv = tid >> 6;
    const int wr = wv >> 1, wc = wv & 1;
    const int lo = lane & 15, hi = lane >> 4;
    const int rowbase = blockIdx.x * BM;
    const int colbase = blockIdx.y * BN;
    const int ar = tid >> 1;            // A row 0..127
    const int ac = (tid & 1) * 16;      // A col half

    f32x4 acc[4][4];
#pragma unroll
    for (int m = 0; m < 4; ++m)
#pragma unroll
        for (int n = 0; n < 4; ++n) acc[m][n] = (f32x4){0.f, 0.f, 0.f, 0.f};

    float4 av0, av1, av2, av3;
#define LOAD_A(k0)                                                                  \
    {                                                                               \
        const float* ap_ = A + (size_t)(rowbase + ar) * DM + (k0) + ac;             \
        av0 = *(const float4*)(ap_);                                                \
        av1 = *(const float4*)(ap_ + 4);                                            \
        av2 = *(const float4*)(ap_ + 8);                                            \
        av3 = *(const float4*)(ap_ + 12);                                           \
    }
#define WRITE_A(buf)                                                                \
    {                                                                               \
        f16* dp_ = &lds_a[buf][ar][ac];                                             \
        u32x4 t0_ = { pkh(av0.x, av0.y), pkh(av0.z, av0.w),                         \
                      pkh(av1.x, av1.y), pkh(av1.z, av1.w) };                       \
        u32x4 t1_ = { pkh(av2.x, av2.y), pkh(av2.z, av2.w),                         \
                      pkh(av3.x, av3.y), pkh(av3.z, av3.w) };                       \
        *(u32x4*)(dp_) = t0_;                                                       \
        *(u32x4*)(dp_ + 8) = t1_;                                                   \
    }
#define STAGE_W(buf, k0)                                                            \
    {                                                                               \
        int r_ = lane >> 2, kc_ = (lane & 3) * 8;                                   \
        gload16(W + (size_t)(colbase + wv * 16 + r_) * DM + (k0) + kc_,             \
                &lds_b[buf][wv * 16][0]);                                           \
        gload16(W + (size_t)(colbase + (wv + 4) * 16 + r_) * DM + (k0) + kc_,       \
                &lds_b[buf][(wv + 4) * 16][0]);                                     \
    }

    LOAD_A(0)
    STAGE_W(0, 0)
    WRITE_A(0)
    __syncthreads();
    int buf = 0;
    for (int ks = 0; ks < KSTEPS; ++ks) {
        if (ks + 1 < KSTEPS) {
            LOAD_A((ks + 1) * BK)
            STAGE_W(buf ^ 1, (ks + 1) * BK)
        }
        f16x8 af[4], bf[4];
#pragma unroll
        for (int m = 0; m < 4; ++m)
            af[m] = *(const f16x8*)&lds_a[buf][wr * 64 + m * 16 + lo][hi * 8];
#pragma unroll
        for (int n = 0; n < 4; ++n)
            bf[n] = *(const f16x8*)&lds_b[buf][wc * 64 + n * 16 + lo][hi * 8];
#pragma unroll
        for (int m = 0; m < 4; ++m)
#pragma unroll
            for (int n = 0; n < 4; ++n)
                acc[m][n] = mfma16(af[m], bf[n], acc[m][n]);
        if (ks + 1 < KSTEPS) WRITE_A(buf ^ 1)     // vm-wait lands after MFMAs
        __syncthreads();
        buf ^= 1;
    }
#undef LOAD_A
#undef WRITE_A
#undef STAGE_W

#pragma unroll
    for (int n = 0; n < 4; ++n) {
        int col = colbase + wc * 64 + n * 16 + lo;
        float bv = bias[col];
        int hh = col >> 6, dh = col & 63;
#pragma unroll
        for (int m = 0; m < 4; ++m)
#pragma unroll
            for (int r = 0; r < 4; ++r) {
                int row = rowbase + wr * 64 + m * 16 + hi * 4 + r;
                int bi = row >> 11;
                int ss = row & (SEQ - 1);
                float v = (acc[m][n][r] + bv) * scale;
                size_t dst;
                if (mode == 2)
                    dst = (((size_t)(bi * NH + hh) * DH + dh) * SEQ + ss);
                else
                    dst = (((size_t)(bi * NH + hh) * SEQ + ss) * DH + dh);
                out[dst] = (f16)v;
            }
    }
}

// ---------------- m97-style GEMM, output projection + bias + residual ----------
__global__ __launch_bounds__(256) void gemm_oproj(
    const f16* __restrict__ A, const f16* __restrict__ W,
    const float* __restrict__ bo, const float* __restrict__ Qin,
    float* __restrict__ out) {
    __shared__ f16 lds_a[2][BM][BK];
    __shared__ f16 lds_b[2][BN][BK];
    const int lane = threadIdx.x & 63;
    const int wv = threadIdx.x >> 6;
    const int wr = wv >> 1, wc = wv & 1;
    const int lo = lane & 15, hi = lane >> 4;
    const int rowbase = blockIdx.x * BM;
    const int colbase = blockIdx.y * BN;

    f32x4 acc[4][4];
#pragma unroll
    for (int m = 0; m < 4; ++m)
#pragma unroll
        for (int n = 0; n < 4; ++n) acc[m][n] = (f32x4){0.f, 0.f, 0.f, 0.f};

#define STAGE_TILES(buf, k0)                                                        \
    {                                                                               \
        int r_ = lane >> 2, kc_ = (lane & 3) * 8;                                   \
        gload16(A + (size_t)(rowbase + wv * 16 + r_) * DM + (k0) + kc_,             \
                &lds_a[buf][wv * 16][0]);                                           \
        gload16(A + (size_t)(rowbase + (wv + 4) * 16 + r_) * DM + (k0) + kc_,       \
                &lds_a[buf][(wv + 4) * 16][0]);                                     \
        gload16(W + (size_t)(colbase + wv * 16 + r_) * DM + (k0) + kc_,             \
                &lds_b[buf][wv * 16][0]);                                           \
        gload16(W + (size_t)(colbase + (wv + 4) * 16 + r_) * DM + (k0) + kc_,       \
                &lds_b[buf][(wv + 4) * 16][0]);                                     \
    }

    STAGE_TILES(0, 0)
    __syncthreads();
    int buf = 0;
    for (int ks = 0; ks < KSTEPS; ++ks) {
        if (ks + 1 < KSTEPS) STAGE_TILES(buf ^ 1, (ks + 1) * BK)
        f16x8 af[4], bf[4];
#pragma unroll
        for (int m = 0; m < 4; ++m)
            af[m] = *(const f16x8*)&lds_a[buf][wr * 64 + m * 16 + lo][hi * 8];
#pragma unroll
        for (int n = 0; n < 4; ++n)
            bf[n] = *(const f16x8*)&lds_b[buf][wc * 64 + n * 16 + lo][hi * 8];
#pragma unroll
        for (int m = 0; m < 4; ++m)
#pragma unroll
            for (int n = 0; n < 4; ++n)
                acc[m][n] = mfma16(af[m], bf[n], acc[m][n]);
        __syncthreads();
        buf ^= 1;
    }
#undef STAGE_TILES

#pragma unroll
    for (int n = 0; n < 4; ++n) {
        int col = colbase + wc * 64 + n * 16 + lo;
        float bv = bo[col];
#pragma unroll
        for (int m = 0; m < 4; ++m)
#pragma unroll
            for (int r = 0; r < 4; ++r) {
                int row = rowbase + wr * 64 + m * 16 + hi * 4 + r;
                size_t idx = (size_t)row * DM + col;
                out[idx] = acc[m][n][r] + bv + Qin[idx];
            }
    }
}

// ---------------- fused flash attention: 32-key tiles, 3-buffer counted-vmcnt ---
// grid: (SEQ/128, BB*NH), block 256 (4 waves x 32 q-rows). LDS 24 KB -> 3-4 blk/CU.
// K tile [32 keys][64 dh] (slot XOR row&7), V^T tile [64 dh][32 keys] (slot XOR row&3).
__global__ __launch_bounds__(256, 3) void attn_kernel(
    const f16* __restrict__ q16, const f16* __restrict__ k16,
    const f16* __restrict__ v16t, const unsigned* __restrict__ pm,
    f16* __restrict__ out16) {
    __shared__ f16 smem[NBUF][2][KVBLK * 64];    // [buf][K/V][2048 f16] = 24 KB
    const int tid = threadIdx.x;
    const int lane = tid & 63;
    const int wv = tid >> 6;
    const int lo = lane & 31, hw = lane >> 5;
    const int bh = blockIdx.y;
    const int b = bh >> 4, hd = bh & 15;
    const int q0 = blockIdx.x * 128 + wv * 32;

    const f16* qp = q16 + ((size_t)bh * SEQ + q0 + lo) * DH + hw * 8;
    const f16* kp = k16 + (size_t)bh * SEQ * DH;
    const f16* vp = v16t + (size_t)bh * DH * SEQ;
    const unsigned* pmb = pm + b * 64;

    // K staging: 8 lanes/row, rows [wv*8, wv*8+8)
    const int sr = lane >> 3, scb = lane & 7;
    const int cb = scb ^ sr;
    // V staging: 4 lanes/row, rows [wv*16, wv*16+16)
    const int svr = lane >> 2, svc = lane & 3;
    const int cbv = svc ^ (svr & 3);

    f16x8 qb[4];
#pragma unroll
    for (int c = 0; c < 4; ++c) qb[c] = *(const f16x8*)(qp + c * 16);

    f32x16 fz;
#pragma unroll
    for (int i = 0; i < 16; ++i) fz[i] = 0.f;
    f32x16 ctx0 = fz, ctx1 = fz, lacc = fz;
    float m = -3e38f;
    f16x8 ones8;
#pragma unroll
    for (int i = 0; i < 8; ++i) ones8[i] = (f16)1.0f;

#define STAGE(buf, KB)                                                              \
    {                                                                               \
        gload16(kp + (size_t)((KB) + wv * 8 + sr) * DH + cb * 8,                    \
                &smem[buf][0][wv * 512]);                                           \
        gload16(vp + (size_t)(wv * 16 + svr) * SEQ + (KB) + cbv * 8,                \
                &smem[buf][1][wv * 512]);                                           \
    }

    STAGE(0, 0)
    STAGE(1, KVBLK)

    int bc = 0;                       // t % NBUF
    for (int t = 0; t < NT; ++t) {
        // counted wait: STAGE(t) (2 loads) landed; STAGE(t+1) may stay in flight
        if (t < NT - 1) asm volatile("s_waitcnt vmcnt(2)" ::: "memory");
        else            asm volatile("s_waitcnt vmcnt(0)" ::: "memory");
        __builtin_amdgcn_s_barrier();
        asm volatile("" ::: "memory");

        // ---- K fragments: row lo, d-slot (2c+hw)^(lo&7) ----
        f16x8 kf[4];
#pragma unroll
        for (int c = 0; c < 4; ++c)
            kf[c] = *(const f16x8*)&smem[bc][0][lo * 64 + (((2 * c + hw) ^ (lo & 7)) << 3)];
        // ---- V fragments: h=0 rows lo, h=1 rows 32+lo; k-slot (2kk+hw)^(row&3) ----
        f16x8 vf[2][2];
#pragma unroll
        for (int h = 0; h < 2; ++h)
#pragma unroll
            for (int kk = 0; kk < 2; ++kk) {
                int row = h * 32 + lo;
                vf[h][kk] = *(const f16x8*)&smem[bc][1][row * 32 + (((2 * kk + hw) ^ (lo & 3)) << 3)];
            }

        // ---- prefetch 2 tiles ahead ----
        if (t + 2 < NT) {
            int bs = bc + 2; if (bs >= NBUF) bs -= NBUF;
            STAGE(bs, (t + 2) * KVBLK)
        }

        // ---- QK^T (zero-register C) ----
        f32x16 st;
        __builtin_amdgcn_s_setprio(1);
        st = mfma32(kf[0], qb[0], fz);
        st = mfma32(kf[1], qb[1], st);
        st = mfma32(kf[2], qb[2], st);
        st = mfma32(kf[3], qb[3], st);
        __builtin_amdgcn_s_setprio(0);

        // ---- mask (packed bits, scalar load) ----
        unsigned bm = pmb[t];
        if (bm != 0xffffffffu) {
            unsigned bs_ = bm >> (hw * 4);
#pragma unroll
            for (int r = 0; r < 16; ++r)
                if (!((bs_ >> ((r & 3) + 8 * (r >> 2))) & 1)) st[r] = -1e9f;
        }

        // ---- online softmax max ----
        float tm = fmaxf(st[0], st[1]);
#pragma unroll
        for (int i = 2; i < 16; i += 2) tm = fmaxf(fmaxf(tm, st[i]), st[i + 1]);
        {
            float2 pp = plswapf(tm);
            tm = fmaxf(pp.x, pp.y);
        }

        if (!__all(tm <= m)) {          // defer-max: rescale only on new max
            float mn = fmaxf(m, tm);
            float sc = exp2f(m - mn);
#pragma unroll
            for (int i = 0; i < 16; ++i) { ctx0[i] *= sc; ctx1[i] *= sc; }
            lacc[0] *= sc;
            m = mn;
        }
#pragma unroll
        for (int i = 0; i < 16; ++i) st[i] = exp2f(st[i] - m);

        // ---- P -> B-fragment, PV MFMAs, l via ones-MFMA ----
        __builtin_amdgcn_s_setprio(1);
        {
            unsigned w0 = pkh(st[0], st[1]),   w1 = pkh(st[2], st[3]);
            unsigned w2 = pkh(st[4], st[5]),   w3 = pkh(st[6], st[7]);
            unsigned w4 = pkh(st[8], st[9]),   w5 = pkh(st[10], st[11]);
            unsigned w6 = pkh(st[12], st[13]), w7 = pkh(st[14], st[15]);
            {
                unsigned a0 = w0, b0 = w2; plswap(a0, b0);
                unsigned a1 = w1, b1 = w3; plswap(a1, b1);
                u32x4 t_ = { a0, a1, b0, b1 };
                f16x8 pb = __builtin_bit_cast(f16x8, t_);
                ctx0 = mfma32(vf[0][0], pb, ctx0);
                ctx1 = mfma32(vf[1][0], pb, ctx1);
                lacc = mfma32(ones8, pb, lacc);
            }
            {
                unsigned a0 = w4, b0 = w6; plswap(a0, b0);
                unsigned a1 = w5, b1 = w7; plswap(a1, b1);
                u32x4 t_ = { a0, a1, b0, b1 };
                f16x8 pb = __builtin_bit_cast(f16x8, t_);
                ctx0 = mfma32(vf[0][1], pb, ctx0);
                ctx1 = mfma32(vf[1][1], pb, ctx1);
                lacc = mfma32(ones8, pb, lacc);
            }
        }
        __builtin_amdgcn_s_setprio(0);

        bc = (bc + 1 == NBUF) ? 0 : bc + 1;
    }
#undef STAGE

    __syncthreads();   // all waves done with smem tiles before transpose reuse

    // ---- epilogue: divide by l, transpose via LDS (reuse smem), f16 stores ----
    float rl = 1.0f / lacc[0];
    f16* tbp = &smem[0][0][0] + wv * (32 * 66);
#pragma unroll
    for (int u = 0; u < 8; ++u) {
        int d0 = 2 * (u & 1) + 8 * (u >> 1) + 4 * hw;
        unsigned pw0 = pkh(ctx0[2 * u] * rl, ctx0[2 * u + 1] * rl);
        unsigned pw1 = pkh(ctx1[2 * u] * rl, ctx1[2 * u + 1] * rl);
        *(unsigned*)&tbp[lo * 66 + d0] = pw0;
        *(unsigned*)&tbp[lo * 66 + 32 + d0] = pw1;
    }
    __syncthreads();
#pragma unroll
    for (int it = 0; it < 4; ++it) {
        int r = it * 8 + (lane >> 3);
        const unsigned* src = (const unsigned*)(tbp + r * 66);
        int cc = (lane & 7) * 4;
        u32x4 t = { src[cc], src[cc + 1], src[cc + 2], src[cc + 3] };
        f16x8 vvv = __builtin_bit_cast(f16x8, t);
        *(f16x8*)(out16 + ((size_t)(b * SEQ) + q0 + r) * DM + hd * 64 + (lane & 7) * 8) = vvv;
    }
}

// ---------------- in-place LayerNorm ----------------
__global__ __launch_bounds__(256) void ln_kernel(
    float* __restrict__ x, const float* __restrict__ gamma,
    const float* __restrict__ beta) {
    const int lane = threadIdx.x & 63;
    const int wave = threadIdx.x >> 6;
    const int row = blockIdx.x * 4 + wave;
    float* rp = x + (size_t)row * DM;

    float4 v[4];
#pragma unroll
    for (int j = 0; j < 4; ++j) v[j] = ((const float4*)rp)[lane + 64 * j];

    float sum = 0.f;
#pragma unroll
    for (int j = 0; j < 4; ++j) sum += v[j].x + v[j].y + v[j].z + v[j].w;
#pragma unroll
    for (int off = 1; off < 64; off <<= 1) sum += __shfl_xor(sum, off);
    float mean = sum * (1.f / DM);

    float vs = 0.f;
#pragma unroll
    for (int j = 0; j < 4; ++j) {
        float dx = v[j].x - mean, dy = v[j].y - mean, dz = v[j].z - mean, dw = v[j].w - mean;
        vs += dx * dx + dy * dy + dz * dz + dw * dw;
    }
#pragma unroll
    for (int off = 1; off < 64; off <<= 1) vs += __shfl_xor(vs, off);
    float rstd = rsqrtf(vs * (1.f / DM) + 1e-5f);

#pragma unroll
    for (int j = 0; j < 4; ++j) {
        int idx = lane + 64 * j;
        float4 g = ((const float4*)gamma)[idx];
        float4 bt = ((const float4*)beta)[idx];
        float4 o;
        o.x = (v[j].x - mean) * rstd * g.x + bt.x;
        o.y = (v[j].y - mean) * rstd * g.y + bt.y;
        o.z = (v[j].z - mean) * rstd * g.z + bt.z;
        o.w = (v[j].w - mean) * rstd * g.w + bt.w;
        ((float4*)rp)[idx] = o;
    }
}

extern "C" void kernel_launch(void* const* d_in, const int* in_sizes, int n_in,
                              void* d_out, int out_size, void* d_ws, size_t ws_size,
                              hipStream_t stream) {
    const float* Q    = (const float*)d_in[0];
    const float* K    = (const float*)d_in[1];
    const float* V    = (const float*)d_in[2];
    const int*   mask = (const int*)d_in[3];
    const float* Wq   = (const float*)d_in[4];
    const float* bq   = (const float*)d_in[5];
    const float* Wk   = (const float*)d_in[6];
    const float* bk   = (const float*)d_in[7];
    const float* Wv   = (const float*)d_in[8];
    const float* bv   = (const float*)d_in[9];
    const float* Wo   = (const float*)d_in[10];
    const float* bo   = (const float*)d_in[11];
    const float* gamma = (const float*)d_in[12];
    const float* beta  = (const float*)d_in[13];
    float* out = (float*)d_out;

    char* ws = (char*)d_ws;
    const size_t MB = 1024 * 1024;
    f16* wq16 = (f16*)(ws + 0 * MB);
    f16* wk16 = (f16*)(ws + 2 * MB);
    f16* wv16 = (f16*)(ws + 4 * MB);
    f16* wo16 = (f16*)(ws + 6 * MB);
    f16* c16  = (f16*)(ws + 8 * MB);
    f16* q16  = (f16*)(ws + 24 * MB);
    f16* k16  = (f16*)(ws + 40 * MB);
    f16* v16t = (f16*)(ws + 56 * MB);  // total 72 MB

    // packed mask lives in the tail of d_out; oproj overwrites all of out later
    unsigned* pm = (unsigned*)((char*)d_out + (size_t)out_size * 4 - 4096);

    cvt_weights<<<dim3(DM * DM / (256 * 4)), dim3(256), 0, stream>>>(
        Wq, Wk, Wv, Wo, wq16, wk16, wv16, wo16);
    pack_mask<<<dim3(4), dim3(64), 0, stream>>>(mask, pm);

    const dim3 ggrid(ROWS / BM, DM / BN);
    const float qscale = 0.125f * 1.44269504f;   // 1/sqrt(DH) * log2(e)

    gemm_proj<<<ggrid, dim3(256), 0, stream>>>(Q, wq16, bq, q16, qscale, 0);
    gemm_proj<<<ggrid, dim3(256), 0, stream>>>(K, wk16, bk, k16, 1.0f, 0);
    gemm_proj<<<ggrid, dim3(256), 0, stream>>>(V, wv16, bv, v16t, 1.0f, 2);

    attn_kernel<<<dim3(SEQ / 128, BB * NH), dim3(256), 0, stream>>>(
        q16, k16, v16t, pm, c16);

    gemm_oproj<<<ggrid, dim3(256), 0, stream>>>(c16, wo16, bo, Q, out);

    ln_kernel<<<dim3(ROWS / 4), dim3(256), 0, stream>>>(out, gamma, beta);
}